// Round 1
// baseline (204.504 us; speedup 1.0000x reference)
//
#include <hip/hip_runtime.h>
#include <hip/hip_bf16.h>
#include <math.h>

#define KSPLIT 16
#define KCHUNK 256
#define BJ 128

// ---------------------------------------------------------------------------
// Split-K batched GEMV: part[ks][b][col] = sum_{k in chunk ks} x[b][k]*w[col][k]
// Three weight pointers so QKV fuses into one launch.
// x: [32][4096], w rows are length-4096, part: [KSPLIT][32][ncols]
// ---------------------------------------------------------------------------
__global__ __launch_bounds__(256) void gemv_part_kernel(
    const float* __restrict__ x,
    const float* __restrict__ w0,
    const float* __restrict__ w1,
    const float* __restrict__ w2,
    int jb1, int jb2,
    int off0, int off1, int off2,
    int ncols,
    float* __restrict__ part)
{
  __shared__ float xt[KCHUNK][32];  // transposed x chunk: [k][b]
  int jb = blockIdx.x, ks = blockIdx.y;
  int k0 = ks * KCHUNK;
  const float* w; int colOff, jbase;
  if (jb < jb1)      { w = w0; colOff = off0; jbase = jb * BJ; }
  else if (jb < jb2) { w = w1; colOff = off1; jbase = (jb - jb1) * BJ; }
  else               { w = w2; colOff = off2; jbase = (jb - jb2) * BJ; }
  int tid = threadIdx.x;
  {
    int b = tid & 31, kg = tid >> 5;
    const float* xr = x + (size_t)b * 4096 + k0 + kg * 32;
    #pragma unroll
    for (int i = 0; i < 8; i++) {
      float4 v = *(const float4*)(xr + i * 4);
      int k = kg * 32 + i * 4;
      xt[k + 0][b] = v.x; xt[k + 1][b] = v.y;
      xt[k + 2][b] = v.z; xt[k + 3][b] = v.w;
    }
  }
  __syncthreads();
  int bg = tid & 7, jg = tid >> 3;            // 8 b-groups x 32 j-groups
  const float* wb = w + (size_t)(jbase + jg * 4) * 4096 + k0;
  float acc[4][4] = {};
  #pragma unroll 4
  for (int k4 = 0; k4 < KCHUNK / 4; k4++) {
    float wr[4][4], xv[4][4];
    #pragma unroll
    for (int jj = 0; jj < 4; jj++) {
      float4 t = *(const float4*)(wb + (size_t)jj * 4096 + k4 * 4);
      wr[jj][0] = t.x; wr[jj][1] = t.y; wr[jj][2] = t.z; wr[jj][3] = t.w;
    }
    #pragma unroll
    for (int c = 0; c < 4; c++) {
      float4 t = *(const float4*)(&xt[k4 * 4 + c][bg * 4]);
      xv[c][0] = t.x; xv[c][1] = t.y; xv[c][2] = t.z; xv[c][3] = t.w;
    }
    #pragma unroll
    for (int jj = 0; jj < 4; jj++)
      #pragma unroll
      for (int bb = 0; bb < 4; bb++)
        acc[jj][bb] += wr[jj][0] * xv[0][bb] + wr[jj][1] * xv[1][bb]
                     + wr[jj][2] * xv[2][bb] + wr[jj][3] * xv[3][bb];
  }
  #pragma unroll
  for (int jj = 0; jj < 4; jj++) {
    int col = colOff + jbase + jg * 4 + jj;
    #pragma unroll
    for (int bb = 0; bb < 4; bb++) {
      int b_ = bg * 4 + bb;
      part[((size_t)ks * 32 + b_) * ncols + col] = acc[jj][bb];
    }
  }
}

// ---------------------------------------------------------------------------
// Reduce split-K partials; apply RoPE to cols < ropeEnd (pairs within heads).
// ---------------------------------------------------------------------------
__global__ __launch_bounds__(256) void reduce_rope_kernel(
    const float* __restrict__ part, int ncols,
    const float* __restrict__ cosv, const float* __restrict__ sinv,
    int ropeEnd, float* __restrict__ outb)
{
  int idx = blockIdx.x * 256 + threadIdx.x;   // pair index
  int np = ncols >> 1;
  int b = idx / np;
  int cp = idx - b * np;
  int col = cp * 2;
  float e = 0.f, o = 0.f;
  #pragma unroll
  for (int ks = 0; ks < KSPLIT; ks++) {
    float2 v = *(const float2*)(part + ((size_t)ks * 32 + b) * ncols + col);
    e += v.x; o += v.y;
  }
  if (col < ropeEnd) {
    int fi = (col & 127) >> 1;
    float c = cosv[fi], s = sinv[fi];
    float ne = e * c - o * s;
    float no = e * s + o * c;
    e = ne; o = no;
  }
  *(float2*)(outb + (size_t)b * ncols + col) = make_float2(e, o);
}

// ---------------------------------------------------------------------------
// Flash-decode attention. Grid: 2 t-splits x 32 b x 8 kv heads = 512 blocks.
// Per block: 4 q-heads. Per wave: 256 t's in 4 chunks of 64 (lane owns a t).
// New token (t == start_pos) merged from RoPE'd k/v (cache not mutated).
// attn_part: [2][32][8][4][130] = {m, l, o[128]}
// ---------------------------------------------------------------------------
__global__ __launch_bounds__(256) void attn_kernel(
    const float* __restrict__ qkv,       // [32][6144]
    const float* __restrict__ cache_k,   // [32][2048][8][128]
    const float* __restrict__ cache_v,
    const int* __restrict__ spp,
    float* __restrict__ attn_part)
{
  __shared__ float q_s[4][128];
  __shared__ float kn_s[128], vn_s[128];
  __shared__ float p_s[4][4][64];
  __shared__ float comb_m[4][4], comb_l[4][4];
  __shared__ float comb_o[4][4][128];
  int bid = blockIdx.x;
  int ts = bid & 1, h = (bid >> 1) & 7, b = bid >> 4;
  int sp = *spp;                              // 2047
  const float scale = 0.088388347648318447f;  // 1/sqrt(128)
  int tid = threadIdx.x;
  {
    int i0 = tid * 2;
    int r = i0 >> 7, d = i0 & 127;
    q_s[r][d]     = qkv[(size_t)b * 6144 + (h * 4 + r) * 128 + d]     * scale;
    q_s[r][d + 1] = qkv[(size_t)b * 6144 + (h * 4 + r) * 128 + d + 1] * scale;
  }
  if (tid < 128) {
    kn_s[tid] = qkv[(size_t)b * 6144 + 4096 + h * 128 + tid];
    vn_s[tid] = qkv[(size_t)b * 6144 + 5120 + h * 128 + tid];
  }
  __syncthreads();
  int wave = tid >> 6, lane = tid & 63;
  int base0 = ts * 1024 + wave * 256;
  float m[4]    = {-INFINITY, -INFINITY, -INFINITY, -INFINITY};
  float lsum[4] = {0.f, 0.f, 0.f, 0.f};
  float o0[4] = {0.f, 0.f, 0.f, 0.f}, o1[4] = {0.f, 0.f, 0.f, 0.f};
  const float* Kb = cache_k + (size_t)b * 2048 * 1024 + h * 128;
  const float* Vb = cache_v + (size_t)b * 2048 * 1024 + h * 128;

  for (int c = 0; c < 4; c++) {
    int tbase = base0 + c * 64;
    int t = tbase + lane;
    float s[4];
    if (t < sp) {                             // cache positions 0..sp-1
      s[0] = s[1] = s[2] = s[3] = 0.f;
      const float* Kr = Kb + (size_t)t * 1024;
      #pragma unroll 8
      for (int d4 = 0; d4 < 32; d4++) {
        float4 kv = *(const float4*)(Kr + d4 * 4);
        #pragma unroll
        for (int r = 0; r < 4; r++) {
          float4 qv = *(const float4*)(&q_s[r][d4 * 4]);
          s[r] += kv.x * qv.x + kv.y * qv.y + kv.z * qv.z + kv.w * qv.w;
        }
      }
    } else {
      s[0] = s[1] = s[2] = s[3] = -INFINITY;
    }
    #pragma unroll
    for (int r = 0; r < 4; r++) {
      float cm = s[r];
      #pragma unroll
      for (int off = 32; off >= 1; off >>= 1) cm = fmaxf(cm, __shfl_xor(cm, off));
      float nm = fmaxf(m[r], cm);
      float alpha, p;
      if (nm == -INFINITY) { alpha = 1.f; p = 0.f; }
      else {
        alpha = __expf(m[r] - nm);                       // exp(-inf)=0 ok
        p = (s[r] == -INFINITY) ? 0.f : __expf(s[r] - nm);
      }
      m[r] = nm;
      lsum[r] = lsum[r] * alpha + p;
      o0[r] *= alpha; o1[r] *= alpha;
      p_s[wave][r][lane] = p;
    }
    // PV: lane owns d-pair (2*lane, 2*lane+1); coalesced V rows
    #pragma unroll 8
    for (int tt = 0; tt < 64; tt++) {
      const float* Vr = Vb + (size_t)(tbase + tt) * 1024;
      float2 vv = *(const float2*)(Vr + lane * 2);
      #pragma unroll
      for (int r = 0; r < 4; r++) {
        float p = p_s[wave][r][tt];
        o0[r] += p * vv.x; o1[r] += p * vv.y;
      }
    }
  }

  // merge the new token (position sp) from RoPE'd k/v, wave 0 of owning block
  if (wave == 0 && sp >= ts * 1024 && sp < ts * 1024 + 1024) {
    float sNew[4];
    #pragma unroll
    for (int r = 0; r < 4; r++) {
      float a = q_s[r][lane * 2] * kn_s[lane * 2]
              + q_s[r][lane * 2 + 1] * kn_s[lane * 2 + 1];
      #pragma unroll
      for (int off = 32; off >= 1; off >>= 1) a += __shfl_xor(a, off);
      sNew[r] = a;
    }
    #pragma unroll
    for (int r = 0; r < 4; r++) {
      float nm = fmaxf(m[r], sNew[r]);
      float alpha = (m[r] == -INFINITY) ? 0.f : __expf(m[r] - nm);
      float p = __expf(sNew[r] - nm);
      m[r] = nm;
      lsum[r] = lsum[r] * alpha + ((lane == 0) ? p : 0.f);
      o0[r] = o0[r] * alpha + p * vn_s[lane * 2];
      o1[r] = o1[r] * alpha + p * vn_s[lane * 2 + 1];
    }
  }

  // per-wave wrap-up: reduce l over lanes, publish (m, l, o) to LDS
  #pragma unroll
  for (int r = 0; r < 4; r++) {
    float L = lsum[r];
    #pragma unroll
    for (int off = 32; off >= 1; off >>= 1) L += __shfl_xor(L, off);
    if (lane == 0) { comb_m[wave][r] = m[r]; comb_l[wave][r] = L; }
    comb_o[wave][r][lane * 2]     = o0[r];
    comb_o[wave][r][lane * 2 + 1] = o1[r];
  }
  __syncthreads();
  // combine 4 waves; thread = (r, d-pair)
  {
    int r = tid >> 6, dp = tid & 63;
    float gm = fmaxf(fmaxf(comb_m[0][r], comb_m[1][r]),
                     fmaxf(comb_m[2][r], comb_m[3][r]));
    float L = 0.f, O0 = 0.f, O1 = 0.f;
    #pragma unroll
    for (int wv = 0; wv < 4; wv++) {
      float mm = comb_m[wv][r];
      float al = (mm == -INFINITY) ? 0.f : __expf(mm - gm);
      L  += comb_l[wv][r] * al;
      O0 += comb_o[wv][r][dp * 2]     * al;
      O1 += comb_o[wv][r][dp * 2 + 1] * al;
    }
    float* ap = attn_part + ((((size_t)ts * 32 + b) * 8 + h) * 4 + r) * 130;
    if (dp == 0) { ap[0] = gm; ap[1] = L; }
    ap[2 + dp * 2] = O0;
    ap[3 + dp * 2] = O1;
  }
}

// ---------------------------------------------------------------------------
// Combine the two t-split partials and divide by l.
// ---------------------------------------------------------------------------
__global__ __launch_bounds__(256) void attn_combine_kernel(
    const float* __restrict__ attn_part, float* __restrict__ attn)
{
  int idx = blockIdx.x * 256 + threadIdx.x;   // 131072 = 32*8*4*128
  int d = idx & 127;
  int r = (idx >> 7) & 3;
  int h = (idx >> 9) & 7;
  int b = idx >> 12;
  const float* p0 = attn_part + (((size_t)(0 * 32 + b) * 8 + h) * 4 + r) * 130;
  const float* p1 = attn_part + (((size_t)(1 * 32 + b) * 8 + h) * 4 + r) * 130;
  float m0 = p0[0], l0 = p0[1], m1 = p1[0], l1 = p1[1];
  float gm = fmaxf(m0, m1);
  float a0 = __expf(m0 - gm), a1 = __expf(m1 - gm);
  float L = l0 * a0 + l1 * a1;
  float o = p0[2 + d] * a0 + p1[2 + d] * a1;
  attn[idx] = o / L;                          // idx == b*4096 + (h*4+r)*128 + d
}

extern "C" void kernel_launch(void* const* d_in, const int* in_sizes, int n_in,
                              void* d_out, int out_size, void* d_ws, size_t ws_size,
                              hipStream_t stream)
{
  const float* x   = (const float*)d_in[0];
  const float* wq  = (const float*)d_in[1];
  const float* wk  = (const float*)d_in[2];
  const float* wv  = (const float*)d_in[3];
  const float* wo  = (const float*)d_in[4];
  const float* fc  = (const float*)d_in[5];
  const float* fs  = (const float*)d_in[6];
  const float* ck  = (const float*)d_in[7];
  const float* cv  = (const float*)d_in[8];
  const int*   spp = (const int*)d_in[9];
  float* out = (float*)d_out;

  float* ws = (float*)d_ws;
  float* qkv_part  = ws;                    // [16][32][6144] = 3145728 f
  float* out_part  = ws;                    // alias: disjoint lifetime
  float* qkvbuf    = ws + 3145728;          // [32][6144]     = 196608 f
  float* attn_part = qkvbuf + 196608;       // [2][32][8][4][130] = 266240 f
  float* attnbuf   = attn_part + 266240;    // [32][4096]     = 131072 f

  // QKV projections (fused, split-K)
  gemv_part_kernel<<<dim3(48, KSPLIT), 256, 0, stream>>>(
      x, wq, wk, wv, 32, 40, 0, 4096, 5120, 6144, qkv_part);
  // reduce + RoPE (q and k rotated, v passthrough)
  reduce_rope_kernel<<<384, 256, 0, stream>>>(qkv_part, 6144, fc, fs, 5120, qkvbuf);
  // attention over KV cache + new token
  attn_kernel<<<512, 256, 0, stream>>>(qkvbuf, ck, cv, spp, attn_part);
  attn_combine_kernel<<<512, 256, 0, stream>>>(attn_part, attnbuf);
  // output projection (split-K)
  gemv_part_kernel<<<dim3(32, KSPLIT), 256, 0, stream>>>(
      attnbuf, wo, wo, wo, 32, 32, 0, 0, 0, 4096, out_part);
  reduce_rope_kernel<<<256, 256, 0, stream>>>(out_part, 4096, fc, fs, 0, out);
}